// Round 5
// baseline (389.193 us; speedup 1.0000x reference)
//
#include <hip/hip_runtime.h>

#define B_    256
#define N_    196
#define DIM_  384
#define H_    12
#define KD_   32
#define VD_   32
#define F_    1152
#define ROWS_ (B_ * N_)
#define VSTR_ 264      // Vt/Pb row stride in bf16: 132 dwords == 4 mod 32 -> 2-way (free) on b128
#define EPS_  1e-5f
// scale * log2(e): softmax computed as exp2(qk*SCALE2 + bias*LOG2E), no max-sub
#define SCALE2_ 0.25506973821659267f
#define LOG2E_  1.4426950408889634f

typedef __bf16 bf16_t;
typedef __bf16 bf16x2 __attribute__((ext_vector_type(2)));
typedef __bf16 bf16x4 __attribute__((ext_vector_type(4)));
typedef __bf16 bf16x8 __attribute__((ext_vector_type(8)));
typedef float  f32x4  __attribute__((ext_vector_type(4)));

__device__ __forceinline__ f32x4 mfma16(bf16x8 a, bf16x8 b, f32x4 c) {
    return __builtin_amdgcn_mfma_f32_16x16x32_bf16(a, b, c, 0, 0, 0);
}
// async global->LDS, 16B/lane; HW writes lane i at (uniform base) + i*16.
__device__ __forceinline__ void gl2lds(const bf16_t* g, bf16_t* l) {
    __builtin_amdgcn_global_load_lds(
        (const __attribute__((address_space(1))) void*)g,
        (__attribute__((address_space(3))) void*)l, 16, 0, 0);
}

// ---------------------------------------------------------------------------
// Weight fp32 -> bf16 convert.
// ---------------------------------------------------------------------------
__global__ __launch_bounds__(256) void cvt_w(const float* __restrict__ src,
                                             bf16_t* __restrict__ dst) {
    const int i = (blockIdx.x * 256 + threadIdx.x) * 4;
    const float4 v = *(const float4*)(src + i);
    bf16x4 o = {(bf16_t)v.x, (bf16_t)v.y, (bf16_t)v.z, (bf16_t)v.w};
    *(bf16x4*)(dst + i) = o;
}

// ---------------------------------------------------------------------------
// LayerNorm: one wave per row, 4 rows per block. fp32 in -> bf16 out.
// ---------------------------------------------------------------------------
__global__ __launch_bounds__(256) void ln_kernel(const float* __restrict__ x,
                                                 const float* __restrict__ w,
                                                 const float* __restrict__ bvec,
                                                 bf16_t* __restrict__ xn) {
    const int lane = threadIdx.x & 63;
    const int row  = blockIdx.x * 4 + (threadIdx.x >> 6);
    const float* xr = x + (size_t)row * DIM_;
    const float4 a = *(const float4*)(xr + lane * 4);
    const float2 c = *(const float2*)(xr + 256 + lane * 2);
    float s  = a.x + a.y + a.z + a.w + c.x + c.y;
    float s2 = a.x*a.x + a.y*a.y + a.z*a.z + a.w*a.w + c.x*c.x + c.y*c.y;
    #pragma unroll
    for (int o = 32; o > 0; o >>= 1) {
        s  += __shfl_xor(s, o);
        s2 += __shfl_xor(s2, o);
    }
    const float mu = s * (1.f / 384.f);
    const float rs = rsqrtf(s2 * (1.f / 384.f) - mu * mu + EPS_);
    const float4 w4 = *(const float4*)(w + lane * 4);
    const float2 w2 = *(const float2*)(w + 256 + lane * 2);
    const float4 b4 = *(const float4*)(bvec + lane * 4);
    const float2 b2 = *(const float2*)(bvec + 256 + lane * 2);
    bf16_t* orow = xn + (size_t)row * DIM_;
    bf16x4 o4 = {(bf16_t)((a.x - mu) * rs * w4.x + b4.x),
                 (bf16_t)((a.y - mu) * rs * w4.y + b4.y),
                 (bf16_t)((a.z - mu) * rs * w4.z + b4.z),
                 (bf16_t)((a.w - mu) * rs * w4.w + b4.w)};
    *(bf16x4*)(orow + lane * 4) = o4;
    bf16x2 o2 = {(bf16_t)((c.x - mu) * rs * w2.x + b2.x),
                 (bf16_t)((c.y - mu) * rs * w2.y + b2.y)};
    *(bf16x2*)(orow + 256 + lane * 2) = o2;
}

// ---------------------------------------------------------------------------
// biasmat2[h][n][ln][c] (fp32, LOG2E-folded): value for key = c*16+ln,
// pad (key>=196 or c>12) = -1e30. grid (12,196) x 256 threads.
// ---------------------------------------------------------------------------
__global__ __launch_bounds__(256) void bias_gather(const float* __restrict__ biases,
                                                   const int* __restrict__ idxs,
                                                   float* __restrict__ bm2) {
    const int h  = blockIdx.x;
    const int n  = blockIdx.y;
    const int ln = threadIdx.x >> 4;
    const int c  = threadIdx.x & 15;
    const int key = c * 16 + ln;
    float v = -1e30f;
    if (key < N_ && c < 13)
        v = biases[h * N_ + idxs[n * N_ + key]] * LOG2E_;
    bm2[(((size_t)h * N_ + n) * 16 + ln) * 16 + c] = v;
}

// ---------------------------------------------------------------------------
// MFMA GEMM, fragment-order LDS (conflict-free ds_read_b128):
// chunk c holds rows [c*16,c*16+16) x 32 k, stored so fragment-lane i's 16B
// sits at chunk_base + i*16. Staged by gl2lds where lane i fetches exactly
// row c*16+(i&15), cols (i>>4)*8. XCD-contiguous tile remap for L2 reuse.
// ---------------------------------------------------------------------------
template <typename OutT>
__global__ __launch_bounds__(256) void gemm_mfma(const bf16_t* __restrict__ A,
                                                 const bf16_t* __restrict__ Wt,
                                                 const float* __restrict__ bias,
                                                 OutT* __restrict__ C,
                                                 int Nout, int K, int ncols) {
    __shared__ __align__(16) bf16_t As2[8 * 512];
    __shared__ __align__(16) bf16_t Bs2[8 * 512];
    const int tid  = threadIdx.x;
    const int lane = tid & 63;
    const int wv   = tid >> 6;
    const int ln   = lane & 15;
    const int ko   = lane >> 4;
    const int wr   = (wv >> 1) * 64;
    const int wc   = (wv & 1) * 64;

    // XCD-contiguous remap: XCD (id&7) gets a contiguous run of tiles
    const int nb   = gridDim.x;
    const int id   = blockIdx.x;
    const int tile = (id & 7) * (nb >> 3) + (id >> 3);
    const size_t bm = (size_t)(tile / ncols) * 128;
    const size_t bn = (size_t)(tile % ncols) * 128;

    // staging: wave wv stages A/B chunks {wv, wv+4}; lane i -> row (i&15), k-col (i>>4)*8
    const bf16_t* gA0 = A  + (bm + wv * 16 + ln) * K + ko * 8;
    const bf16_t* gA1 = gA0 + (size_t)64 * K;
    const bf16_t* gB0 = Wt + (bn + wv * 16 + ln) * K + ko * 8;
    const bf16_t* gB1 = gB0 + (size_t)64 * K;
    bf16_t* lA0 = As2 + wv * 512;
    bf16_t* lA1 = As2 + (wv + 4) * 512;
    bf16_t* lB0 = Bs2 + wv * 512;
    bf16_t* lB1 = Bs2 + (wv + 4) * 512;

    f32x4 acc[4][4];
    #pragma unroll
    for (int i = 0; i < 4; i++)
        #pragma unroll
        for (int j = 0; j < 4; j++)
            acc[i][j] = (f32x4){0.f, 0.f, 0.f, 0.f};

    for (int k0 = 0; k0 < K; k0 += 32) {
        gl2lds(gA0 + k0, lA0);
        gl2lds(gA1 + k0, lA1);
        gl2lds(gB0 + k0, lB0);
        gl2lds(gB1 + k0, lB1);
        __syncthreads();
        bf16x8 af[4], bfr[4];
        #pragma unroll
        for (int i = 0; i < 4; i++)
            af[i] = *(const bf16x8*)(As2 + ((wr >> 4) + i) * 512 + lane * 8);
        #pragma unroll
        for (int j = 0; j < 4; j++)
            bfr[j] = *(const bf16x8*)(Bs2 + ((wc >> 4) + j) * 512 + lane * 8);
        #pragma unroll
        for (int i = 0; i < 4; i++)
            #pragma unroll
            for (int j = 0; j < 4; j++)
                acc[i][j] = mfma16(af[i], bfr[j], acc[i][j]);
        __syncthreads();
    }

    #pragma unroll
    for (int j = 0; j < 4; j++) {
        const size_t col = bn + wc + j * 16 + ln;
        const float bcol = bias[col];
        #pragma unroll
        for (int i = 0; i < 4; i++)
            #pragma unroll
            for (int r = 0; r < 4; r++) {
                const size_t row = bm + wr + i * 16 + ko * 4 + r;
                C[row * Nout + col] = (OutT)(acc[i][j][r] + bcol);
            }
    }
}

// ---------------------------------------------------------------------------
// MFMA attention: 1 block (4 waves) per (b,h).
// LDS (50688 B -> 3 blocks/CU): Vt[32][264] | union{ Ks frag-order 13x1024B,
// Pb[4][16][264] } -- Pb overlays Ks after the kf hoist (barrier-protected).
// No row-max (scores ~ +-1.5); exp2 with pre-folded log2e.
// ---------------------------------------------------------------------------
__global__ __launch_bounds__(256) void attn_mfma(const bf16_t* __restrict__ qkv,
                                                 const float* __restrict__ bm2,
                                                 bf16_t* __restrict__ out) {
    const int b = blockIdx.x / H_;
    const int h = blockIdx.x % H_;
    __shared__ __align__(16) char smem[16896 + 33792];
    bf16_t* Vt = (bf16_t*)smem;                 // [32][VSTR_]
    bf16_t* Ks = (bf16_t*)(smem + 16896);       // [13][512] fragment-order
    bf16_t* Pb = (bf16_t*)(smem + 16896);       // [4][16][VSTR_] (overlays Ks)
    const int tid  = threadIdx.x;
    const int lane = tid & 63;
    const int wv   = tid >> 6;
    const int ln   = lane & 15;
    const int ko   = lane >> 4;

    // --- stage K fragment-order: chunk c, lane i fetches row c*16+(i&15), k (i>>4)*8
    for (int c = wv; c < 13; c += 4) {
        const int krow = min(c * 16 + ln, N_ - 1);
        gl2lds(qkv + ((size_t)(b * N_ + krow) * H_ + h) * 96 + KD_ + ko * 8,
               Ks + c * 512);
    }
    // --- stage V transposed: thread t owns column kk=t, source row m=bitswap(t)
    {
        const int m = ((tid & 15) << 4) | (tid >> 4);
        const bf16_t* src = qkv + ((size_t)(b * N_ + m) * H_ + h) * 96 + 2 * KD_;
        #pragma unroll
        for (int c4 = 0; c4 < 4; c4++) {
            bf16x8 v8 = {bf16_t(0), bf16_t(0), bf16_t(0), bf16_t(0),
                         bf16_t(0), bf16_t(0), bf16_t(0), bf16_t(0)};
            if (m < N_) v8 = *(const bf16x8*)(src + c4 * 8);
            #pragma unroll
            for (int j = 0; j < 8; j++) Vt[(c4 * 8 + j) * VSTR_ + tid] = v8[j];
        }
    }
    __syncthreads();

    // hoist K fragments (conflict-free: addr = lane*4 dwords within chunk)
    bf16x8 kf[13];
    #pragma unroll
    for (int c = 0; c < 13; c++)
        kf[c] = *(const bf16x8*)(Ks + c * 512 + lane * 8);
    __syncthreads();   // Ks region now dead; Pb may overwrite it

    for (int t = wv; t < 13; t += 4) {
        const int qrow = min(t * 16 + ln, N_ - 1);
        const bf16x8 qf =
            *(const bf16x8*)(qkv + ((size_t)(b * N_ + qrow) * H_ + h) * 96 + ko * 8);

        f32x4 sc[13];
        #pragma unroll
        for (int c = 0; c < 13; c++) {
            f32x4 z = {0.f, 0.f, 0.f, 0.f};
            sc[c] = mfma16(qf, kf[c], z);
        }

        float inv[4];
        #pragma unroll
        for (int r = 0; r < 4; r++) {
            const int rowc = min(t * 16 + ko * 4 + r, N_ - 1);
            const float4* bp =
                (const float4*)(bm2 + (((size_t)h * N_ + rowc) * 16 + ln) * 16);
            float bv[16];
            *(float4*)&bv[0]  = bp[0];
            *(float4*)&bv[4]  = bp[1];
            *(float4*)&bv[8]  = bp[2];
            *(float4*)&bv[12] = bp[3];
            float sum = 0.f;
            #pragma unroll
            for (int c = 0; c < 13; c++) {
                const float p = exp2f(fmaf(sc[c][r], SCALE2_, bv[c]));
                sc[c][r] = p;
                sum += p;
            }
            sum += __shfl_xor(sum, 1);
            sum += __shfl_xor(sum, 2);
            sum += __shfl_xor(sum, 4);
            sum += __shfl_xor(sum, 8);
            inv[r] = 1.f / sum;
        }

        // write unnormalized P into permuted layout: lane ln owns cols [ln*16, ln*16+16)
        #pragma unroll
        for (int r = 0; r < 4; r++) {
            bf16x8 pa, pb2;
            #pragma unroll
            for (int c = 0; c < 8; c++) pa[c] = (bf16_t)sc[c][r];
            #pragma unroll
            for (int c = 8; c < 13; c++) pb2[c - 8] = (bf16_t)sc[c][r];
            pb2[5] = bf16_t(0); pb2[6] = bf16_t(0); pb2[7] = bf16_t(0);
            bf16_t* dst = Pb + ((wv * 16) + ko * 4 + r) * VSTR_ + ln * 16;
            *(bf16x8*)dst       = pa;
            *(bf16x8*)(dst + 8) = pb2;
        }

        // PV over permuted k (256 slots = 8 MFMAs), two 16-wide v tiles
        f32x4 o0 = {0.f, 0.f, 0.f, 0.f};
        f32x4 o1 = {0.f, 0.f, 0.f, 0.f};
        #pragma unroll
        for (int kb = 0; kb < 8; kb++) {
            const bf16x8 pf = *(const bf16x8*)(Pb + (wv * 16 + ln) * VSTR_ + kb * 32 + ko * 8);
            const bf16x8 v0 = *(const bf16x8*)(Vt + ln * VSTR_ + kb * 32 + ko * 8);
            const bf16x8 v1 = *(const bf16x8*)(Vt + (16 + ln) * VSTR_ + kb * 32 + ko * 8);
            o0 = mfma16(pf, v0, o0);
            o1 = mfma16(pf, v1, o1);
        }
        #pragma unroll
        for (int r = 0; r < 4; r++) {
            const int row = t * 16 + ko * 4 + r;
            if (row < N_) {
                const size_t ob = (size_t)(b * N_ + row) * DIM_ + h * VD_;
                out[ob + ln]      = (bf16_t)(o0[r] * inv[r]);
                out[ob + 16 + ln] = (bf16_t)(o1[r] * inv[r]);
            }
        }
    }
}

// ---------------------------------------------------------------------------
extern "C" void kernel_launch(void* const* d_in, const int* in_sizes, int n_in,
                              void* d_out, int out_size, void* d_ws, size_t ws_size,
                              hipStream_t stream) {
    const float* x        = (const float*)d_in[0];
    const float* norm_w   = (const float*)d_in[1];
    const float* norm_b   = (const float*)d_in[2];
    const float* qkv_w    = (const float*)d_in[3];
    const float* qkv_b    = (const float*)d_in[4];
    const float* att_bias = (const float*)d_in[5];
    const float* proj_w   = (const float*)d_in[6];
    const float* proj_b   = (const float*)d_in[7];
    const int*   bias_idx = (const int*)d_in[8];
    float* out = (float*)d_out;

    char* ws = (char*)d_ws;
    size_t off = 0;
    bf16_t* xn       = (bf16_t*)(ws + off); off += (size_t)ROWS_ * DIM_ * 2;
    bf16_t* qkvbuf   = (bf16_t*)(ws + off); off += (size_t)ROWS_ * F_ * 2;
    bf16_t* attn_out = (bf16_t*)(ws + off); off += (size_t)ROWS_ * DIM_ * 2;
    float*  bm2      = (float*)(ws + off);  off += (size_t)H_ * N_ * 256 * 4;
    bf16_t* wq_bf    = (bf16_t*)(ws + off); off += (size_t)F_ * DIM_ * 2;
    bf16_t* wp_bf    = (bf16_t*)(ws + off); off += (size_t)DIM_ * DIM_ * 2;

    cvt_w<<<(F_ * DIM_) / 1024, 256, 0, stream>>>(qkv_w, wq_bf);
    cvt_w<<<(DIM_ * DIM_) / 1024, 256, 0, stream>>>(proj_w, wp_bf);
    ln_kernel<<<ROWS_ / 4, 256, 0, stream>>>(x, norm_w, norm_b, xn);
    bias_gather<<<dim3(H_, N_), 256, 0, stream>>>(att_bias, bias_idx, bm2);
    gemm_mfma<bf16_t><<<(ROWS_ / 128) * (F_ / 128), 256, 0, stream>>>(
        xn, wq_bf, qkv_b, qkvbuf, F_, DIM_, F_ / 128);
    attn_mfma<<<B_ * H_, 256, 0, stream>>>(qkvbuf, bm2, attn_out);
    gemm_mfma<float><<<(ROWS_ / 128) * (DIM_ / 128), 256, 0, stream>>>(
        attn_out, wp_bf, proj_b, out, DIM_, DIM_, DIM_ / 128);
}